// Round 15
// baseline (158.255 us; speedup 1.0000x reference)
//
#include <hip/hip_runtime.h>
#include <float.h>

// B=8, N=1024, D=256, K=16384, H=1024, IN=256
#define DIM      256
#define NK       16384
#define NH       1024
#define NIN      256
#define NBN      8192
#define NT2      128           // NK / 128 (dist n-tiles)

#define OFF_ZREC 0
#define OFF_ZENC (NBN * DIM)
#define OFF_ZEMB (2 * NBN * DIM)

using short8 = __attribute__((ext_vector_type(8))) short;
using f32x4  = __attribute__((ext_vector_type(4))) float;
typedef unsigned long long u64;
typedef unsigned int u32;

#define WAITVM(n)  asm volatile("s_waitcnt vmcnt(" #n ")" ::: "memory")
#define WAITLGKM0  asm volatile("s_waitcnt lgkmcnt(0)" ::: "memory")

template <int N>
__device__ __forceinline__ void waitvm_c() {
    // s_waitcnt imm: vmcnt[3:0]@[3:0], vmcnt[5:4]@[15:14], expcnt@[6:4], lgkmcnt@[11:8]
    __builtin_amdgcn_s_waitcnt(0x0F70 | (N & 0xF) | (((N >> 4) & 3) << 14));
}

__device__ __forceinline__ u32 f2bf(float f) {
    u32 u = __float_as_uint(f);
    return (u + 0x7FFFu + ((u >> 16) & 1u)) >> 16;   // RNE
}
__device__ __forceinline__ float bf2f(u32 h) {
    return __uint_as_float(h << 16);
}
__device__ __forceinline__ u64 umin64(u64 a, u64 b) { return a < b ? a : b; }
__device__ __forceinline__ u32 umin32(u32 a, u32 b) { return a < b ? a : b; }
__device__ __forceinline__ u32 umax32(u32 a, u32 b) { return a > b ? a : b; }

__device__ __forceinline__ void gload16(const void* g, void* l) {
    __builtin_amdgcn_global_load_lds(
        (const __attribute__((address_space(1))) void*)g,
        (__attribute__((address_space(3))) void*)l, 16, 0, 0);
}

// pack one 16x32 chunk of fp32 [rows][KD] into bf16 MFMA fragment(s).
// Fragment (16x16x32 bf16): lane l <-> row = l&15, k = (l>>4)*8 + i.
// dst[rb][unit][lane][8]: hi unit = kc, mid unit = KD/32 + kc.
__device__ __forceinline__ void pack_frag(const float* __restrict__ src,
                                          unsigned short* __restrict__ dst,
                                          int KD, int KBT, int rb, int kc,
                                          int lane, bool with_mid) {
    int row = rb * 16 + (lane & 15);
    int k0  = kc * 32 + (lane >> 4) * 8;
    const float* p = src + (size_t)row * KD + k0;
    float x[8];
    *(float4*)(x)     = *(const float4*)(p);
    *(float4*)(x + 4) = *(const float4*)(p + 4);
    short8 hv, mv;
    #pragma unroll
    for (int i = 0; i < 8; ++i) {
        u32 hb = f2bf(x[i]);
        hv[i] = (short)hb;
        mv[i] = (short)f2bf(x[i] - bf2f(hb));
    }
    *(short8*)(dst + ((size_t)(rb * KBT + kc) * 64 + lane) * 8) = hv;
    if (with_mid)
        *(short8*)(dst + ((size_t)(rb * KBT + KD / 32 + kc) * 64 + lane) * 8) = mv;
}

// ---------------- fused prep: pack X(hi), E(hi), W1(hi), W2(hi) + t2 ----------------
__global__ __launch_bounds__(256) void prep_kernel(
    const float* __restrict__ X, const float* __restrict__ E,
    const float* __restrict__ W1, const float* __restrict__ W2,
    unsigned short* __restrict__ Xp, unsigned short* __restrict__ Ep,
    unsigned short* __restrict__ W1p, unsigned short* __restrict__ W2p,
    float* __restrict__ t2)
{
    int b = blockIdx.x;
    int wid = threadIdx.x >> 6, lane = threadIdx.x & 63;
    if (b < 1024) {                         // X hi: 4096 gids (512 rb x 8 kc)
        int gid = b * 4 + wid;
        pack_frag(X, Xp, 256, 8, gid >> 3, gid & 7, lane, false);
    } else if (b < 3072) {                  // E hi: 8192 gids (1024 rb x 8 kc)
        int gid = (b - 1024) * 4 + wid;
        pack_frag(E, Ep, 256, 8, gid >> 3, gid & 7, lane, false);
    } else if (b < 3200) {                  // W1 hi: 512 gids (64 rb x 8 kc)
        int gid = (b - 3072) * 4 + wid;
        pack_frag(W1, W1p, 256, 8, gid >> 3, gid & 7, lane, false);
    } else if (b < 3328) {                  // W2 hi: 512 gids (16 rb x 32 kc)
        int gid = (b - 3200) * 4 + wid;
        pack_frag(W2, W2p, 1024, 32, gid >> 5, gid & 31, lane, false);
    } else {                                // t2: 1024 blocks x 4 gids x 4 rows
        int gid = (b - 3328) * 4 + wid;
        #pragma unroll
        for (int r = 0; r < 4; ++r) {
            int row = gid * 4 + r;
            float4 v = ((const float4*)(E + (size_t)row * DIM))[lane];
            float s = v.x * v.x + v.y * v.y + v.z * v.z + v.w * v.w;
            #pragma unroll
            for (int off = 32; off > 0; off >>= 1) s += __shfl_down(s, off);
            if (lane == 0) t2[row] = s;
        }
    }
}

// ---------------- MFMA distance (bf16 hi-only), 256x128 tile, 8 waves (4m x 2n) ----------
// Wave tile 64x64 (acc[4][4] -> 2 blocks/CU). BK=32, 3x24KB rotating buffers, ONE barrier
// per K-step. CORRECTED vs R14: STAGE(s+2) issues AFTER barrier_s — a wave reaches
// barrier_s only after its iter-(s-1) MFMAs consumed buffer (s-1)%3 == (s+2)%3, so the
// write is WAR-safe; WAITVM(3) before barrier_s makes buffer s%3 RAW-safe across waves.
// No setprio (m190/R11: lockstep -> regression).
__global__ __launch_bounds__(512, 3) void dist_topk_kernel(
    const unsigned short* __restrict__ Xp, const unsigned short* __restrict__ Ep,
    const float* __restrict__ t2, uint2* __restrict__ ptop)
{
    __shared__ __align__(16) char lds[73728];   // main: 3x24KB; epi: 2 x [256][33] u32

    int bx = blockIdx.x;          // 32 mt x 128 nt
    int mt = bx >> 7, nt = bx & 127;
    int mb0 = mt * 16, nb0 = nt * 8;
    int m0 = mt * 256, n0 = nt * 128;

    int tid = threadIdx.x;
    int wid = tid >> 6, lane = tid & 63;
    int wm = wid >> 1, wn = wid & 1;            // 4 x 2 wave grid; wave = 64x64 out

    f32x4 acc[4][4] = {};

    auto STAGE = [&](int s) {                   // stage K32-slice s into buffer s%3
        char* L = lds + (s % 3) * 24576;
        #pragma unroll
        for (int c = 0; c < 3; ++c) {
            int ci = wid * 3 + c;               // 0..23: A rb 0..15, B rb 0..7
            if (ci < 16)
                gload16(Xp + ((size_t)((mb0 + ci) * 8 + s) * 64 + lane) * 8,
                        L + ci * 1024);
            else
                gload16(Ep + ((size_t)((nb0 + (ci - 16)) * 8 + s) * 64 + lane) * 8,
                        L + 16384 + (ci - 16) * 1024);
        }
    };

    STAGE(0); STAGE(1);                         // 6 loads outstanding
    #pragma unroll
    for (int s = 0; s < 8; ++s) {
        if (s < 7) { WAITVM(3); }               // drain own stage-s loads, keep s+1
        else       { WAITVM(0); }
        __builtin_amdgcn_sched_barrier(0);
        __builtin_amdgcn_s_barrier();           // all waves: stage-s landed, iter s-1 reads done
        __builtin_amdgcn_sched_barrier(0);
        if (s < 6) STAGE(s + 2);                // writes (s+2)%3 == (s-1)%3: WAR-safe now
        const char* LA = lds + (s % 3) * 24576;
        const char* LB = LA + 16384;
        short8 a[4], b[4];
        #pragma unroll
        for (int i = 0; i < 4; ++i)
            a[i] = *(const short8*)(LA + ((wm * 4 + i) << 10) + (lane << 4));
        #pragma unroll
        for (int j = 0; j < 4; ++j)
            b[j] = *(const short8*)(LB + ((wn * 4 + j) << 10) + (lane << 4));
        #pragma unroll
        for (int i = 0; i < 4; ++i)
            #pragma unroll
            for (int j = 0; j < 4; ++j)
                acc[i][j] = __builtin_amdgcn_mfma_f32_16x16x32_bf16(
                    a[i], b[j], acc[i][j], 0, 0, 0);
    }
    __syncthreads();                             // protect LDS reuse by epilogue

    // ---- epilogue: per-row top-2 over this block's 128 cols, single pass ----
    // C frag: col = lane&15, row = (lane>>4)*4 + r.  Keys: positive floats
    // (score + 4096 > 0) are uint-ordered; key = (bits & 0xFFFFFF00) | local_col.
    // Write slot rotated by 4*lg: bank = const + col + 8*lg -> 2-way max.
    int col_l = lane & 15, lg = lane >> 4;
    float t2b[4];
    #pragma unroll
    for (int j = 0; j < 4; ++j) t2b[j] = t2[n0 + wn * 64 + j * 16 + col_l] + 4096.0f;

    u32* cand0 = (u32*)lds;                     // [256 rows][33 slots]
    u32* cand1 = cand0 + 256 * 33;
    int slot = (wn * 16 + col_l + 4 * lg) & 31; // per-row bijective, lg-rotated
    #pragma unroll
    for (int i = 0; i < 4; ++i)
        #pragma unroll
        for (int r = 0; r < 4; ++r) {
            u32 b0 = 0xFFFFFFFFu, b1 = 0xFFFFFFFFu;
            #pragma unroll
            for (int j = 0; j < 4; ++j) {
                float sc = fmaf(-2.0f, acc[i][j][r], t2b[j]);
                u32 u = (__float_as_uint(sc) & 0xFFFFFF00u)
                      | (u32)(wn * 64 + j * 16 + col_l);
                u32 t = umin32(b0, u);
                b1 = umin32(b1, umax32(b0, u));
                b0 = t;
            }
            int row = wm * 64 + i * 16 + lg * 4 + r;             // 0..255
            cand0[row * 33 + slot] = b0;
            cand1[row * 33 + slot] = b1;
        }
    __syncthreads();
    // scan: 2 threads per row, sequential slots (bank = row+16*part+t -> 2-way, free)
    {
        int row = tid >> 1, part = tid & 1;
        u32 c0 = 0xFFFFFFFFu, c1 = 0xFFFFFFFFu;
        #pragma unroll 4
        for (int t = 0; t < 16; ++t) {
            int sl = part * 16 + t;
            u32 a0 = cand0[row * 33 + sl];
            u32 a1 = cand1[row * 33 + sl];
            u32 lo = umin32(c0, a0);
            c1 = umin32(umax32(c0, a0), umin32(c1, a1));
            c0 = lo;
        }
        u32 a0 = __shfl_xor(c0, 1);
        u32 a1 = __shfl_xor(c1, 1);
        u32 lo = umin32(c0, a0);
        c1 = umin32(umax32(c0, a0), umin32(c1, a1));
        c0 = lo;
        if (part == 0)                           // transposed: [nt][q] -> coalesced
            ptop[(size_t)nt * NBN + (m0 + row)] = make_uint2(c0, c1);
    }
}

// ---------------- merge -> top-3 -> exact fp64 rescreen -> gather + final idx ----------------
__global__ __launch_bounds__(256) void merge_rescreen_kernel(
    const float* __restrict__ X, const float* __restrict__ E,
    const uint2* __restrict__ ptop, float* __restrict__ out, int* __restrict__ fidx)
{
    int wid = threadIdx.x >> 6, lane = threadIdx.x & 63;
    int q = blockIdx.x * 4 + wid;
    uint2 A = ptop[(size_t)(lane * 2)     * NBN + q];
    uint2 B = ptop[(size_t)(lane * 2 + 1) * NBN + q];
    // rebuild globally-ordered keys: [24b score @ bits 14..37 | 14b global k]
    u64 k[4];
    k[0] = ((u64)(A.x & 0xFFFFFF00u) << 6) | (u32)((lane * 2) * 128 + (A.x & 0xFF));
    k[1] = ((u64)(A.y & 0xFFFFFF00u) << 6) | (u32)((lane * 2) * 128 + (A.y & 0xFF));
    k[2] = ((u64)(B.x & 0xFFFFFF00u) << 6) | (u32)((lane * 2 + 1) * 128 + (B.x & 0xFF));
    k[3] = ((u64)(B.y & 0xFFFFFF00u) << 6) | (u32)((lane * 2 + 1) * 128 + (B.y & 0xFF));
    int cand[3];
    #pragma unroll
    for (int pass = 0; pass < 3; ++pass) {
        u64 m = umin64(umin64(k[0], k[1]), umin64(k[2], k[3]));
        #pragma unroll
        for (int mask = 1; mask < 64; mask <<= 1)
            m = umin64(m, (u64)__shfl_xor((unsigned long long)m, mask));
        cand[pass] = (int)(m & 0x3FFF);
        #pragma unroll
        for (int t = 0; t < 4; ++t) if (k[t] == m) k[t] = ~0ull;
    }
    float4 qv = ((const float4*)(X + (size_t)q * DIM))[lane];
    double bd = 1e300; int bi = NK;
    #pragma unroll 1
    for (int c = 0; c < 3; ++c) {
        int idx = cand[c];
        float4 ev = ((const float4*)(E + (size_t)idx * DIM))[lane];
        double d0 = (double)qv.x - (double)ev.x;
        double d1 = (double)qv.y - (double)ev.y;
        double d2 = (double)qv.z - (double)ev.z;
        double d3 = (double)qv.w - (double)ev.w;
        double s = d0 * d0 + d1 * d1 + d2 * d2 + d3 * d3;
        #pragma unroll
        for (int off = 32; off > 0; off >>= 1) s += __shfl_down(s, off);
        s = __shfl(s, 0);
        if (s < bd || (s == bd && idx < bi)) { bd = s; bi = idx; }
    }
    float4 ev = ((const float4*)(E + (size_t)bi * DIM))[lane];
    ((float4*)(out + OFF_ZEMB + (size_t)q * DIM))[lane] = ev;
    ((float4*)(out + OFF_ZENC + (size_t)q * DIM))[lane] = qv;
    if (lane == 0) fidx[q] = bi;
}

// ---------------- multi-limb bf16 MFMA GEMM: C[M][N] = A[M][KD]*B[N][KD]^T + bias ----------
// GATHER: A-fragments gathered per-lane from Ap (codebook pack) via selidx.
// G1: bias+LeakyReLU, repack hi-limb into Hp (gemm2 A-fragment layout, 32 units).
// Counted-vmcnt dual-barrier pipeline. Geometry: NRB_A x NRB_B row/col blocks, WMxWN waves.
template <int KD, int A_KBT, int B_KBT, int NPROD, int AO1, int BO1,
          int NRB_A, int NRB_B, int WM, int WN, int NT, bool G1, bool GATHER>
__global__ __launch_bounds__(64 * WM * WN) void gemm_mfma_kernel(
    const unsigned short* __restrict__ Ap, const unsigned short* __restrict__ Bp,
    const int* __restrict__ selidx, const float* __restrict__ bias,
    float* __restrict__ C, unsigned short* __restrict__ Hp)
{
    constexpr int KQ    = KD / 64;
    constexpr int STEPS = NPROD * KQ;
    constexpr int WI    = NRB_A / WM;
    constexpr int FJ    = NRB_B / WN;
    constexpr int CA    = NRB_A * 2;
    constexpr int CB    = NRB_B * 2;
    constexpr int NW    = WM * WN;
    constexpr int PW    = (CA + CB) / NW;
    constexpr int BUFSZ = (CA + CB) * 1024;
    constexpr int LDSSZ = G1 ? 65536 : 2 * BUFSZ;

    __shared__ __align__(16) char lds[LDSSZ];

    int bx = blockIdx.x;
    int mt = bx / NT, nt = bx % NT;
    int mb0 = mt * NRB_A, nb0 = nt * NRB_B;
    int m0 = mt * (NRB_A * 16), n0 = nt * (NRB_B * 16);

    int tid = threadIdx.x;
    int wid = tid >> 6, lane = tid & 63;
    int wm = wid / WN, wn = wid % WN;

    f32x4 acc[WI][FJ] = {};

    auto STAGE = [&](int s, int b) {
        int p = s / KQ, kq = s % KQ;
        int akb = (p == 0 ? 0 : AO1) + kq * 2;
        int bkb = (p == 0 ? 0 : BO1) + kq * 2;
        char* LA = lds + b * BUFSZ;
        char* LB = LA + CA * 1024;
        #pragma unroll
        for (int r = 0; r < PW; ++r) {
            int ci = wid * PW + r;
            if (ci < CA) {
                int rbl = ci >> 1, kbl = ci & 1;
                size_t ga;
                if constexpr (GATHER) {
                    int sel = selidx[(mb0 + rbl) * 16 + (lane & 15)];
                    ga = ((size_t)((sel >> 4) * A_KBT + akb + kbl) * 64
                          + (lane >> 4) * 16 + (sel & 15)) * 8;
                } else {
                    ga = ((size_t)((mb0 + rbl) * A_KBT + akb + kbl) * 64 + lane) * 8;
                }
                gload16(Ap + ga, LA + ci * 1024);
            } else {
                int cj = ci - CA, rbl = cj >> 1, kbl = cj & 1;
                gload16(Bp + ((size_t)((nb0 + rbl) * B_KBT + bkb + kbl) * 64 + lane) * 8,
                        LB + cj * 1024);
            }
        }
    };

    STAGE(0, 0);
    for (int s = 0; s < STEPS; ++s) {
        int cur = s & 1;
        if (s + 1 < STEPS) { STAGE(s + 1, cur ^ 1); waitvm_c<PW>(); }
        else               { waitvm_c<0>(); }
        __builtin_amdgcn_s_barrier();
        __builtin_amdgcn_sched_barrier(0);
        const char* LA = lds + cur * BUFSZ;
        const char* LB = LA + CA * 1024;
        #pragma unroll
        for (int kk = 0; kk < 2; ++kk) {
            short8 a[WI], b[FJ];
            #pragma unroll
            for (int i = 0; i < WI; ++i)
                a[i] = *(const short8*)(LA + (((wm * WI + i) * 2 + kk) << 10) + (lane << 4));
            #pragma unroll
            for (int j = 0; j < FJ; ++j)
                b[j] = *(const short8*)(LB + (((wn * FJ + j) * 2 + kk) << 10) + (lane << 4));
            #pragma unroll
            for (int i = 0; i < WI; ++i)
                #pragma unroll
                for (int j = 0; j < FJ; ++j)
                    acc[i][j] = __builtin_amdgcn_mfma_f32_16x16x32_bf16(
                        a[i], b[j], acc[i][j], 0, 0, 0);
        }
        WAITLGKM0;
        __builtin_amdgcn_sched_barrier(0);
        __builtin_amdgcn_s_barrier();
    }

    int col_l = lane & 15, lg = lane >> 4;
    if (!G1) {
        #pragma unroll
        for (int j = 0; j < FJ; ++j) {
            int n = n0 + wn * (FJ * 16) + j * 16 + col_l;
            float bb = bias[n];
            #pragma unroll
            for (int i = 0; i < WI; ++i)
                #pragma unroll
                for (int r = 0; r < 4; ++r) {
                    int m = m0 + wm * (WI * 16) + i * 16 + lg * 4 + r;
                    C[(size_t)m * (NT * NRB_B * 16) + n] = acc[i][j][r] + bb;
                }
        }
    } else {
        // bias + LeakyReLU + bf16(hi) -> swizzled LDS u16 tile -> repack to Hp frags
        // (fixed geometry: NRB_A=8, NRB_B=8, WM=WN=2)
        unsigned short* lds16 = (unsigned short*)lds;
        #pragma unroll
        for (int j = 0; j < FJ; ++j) {
            int coln = wn * 64 + j * 16 + col_l;
            float bb = bias[n0 + coln];
            #pragma unroll
            for (int i = 0; i < WI; ++i)
                #pragma unroll
                for (int r = 0; r < 4; ++r) {
                    int row = wm * 64 + i * 16 + lg * 4 + r;
                    float v = acc[i][j][r] + bb;
                    v = fmaxf(v, 0.1f * v);
                    int sw = ((row >> 2) & 3) << 3;
                    lds16[row * 128 + (coln ^ sw)] = (unsigned short)f2bf(v);
                }
        }
        __syncthreads();
        #pragma unroll
        for (int rbw = 0; rbw < 2; ++rbw) {
            int rrb = wid * 2 + rbw;
            int rloc = lane & 15, ls = lane >> 4;
            int row = rrb * 16 + rloc;
            int sw  = ((row >> 2) & 3) << 3;
            #pragma unroll
            for (int kc = 0; kc < 4; ++kc) {
                int c0 = (kc * 32 + ls * 8) ^ sw;
                short8 h8 = *(const short8*)(lds16 + row * 128 + c0);
                int ku = nt * 4 + kc;              // unit within KD2=1024 hi (32 units)
                *(short8*)(Hp + ((size_t)((mb0 + rrb) * 32 + ku) * 64 + lane) * 8) = h8;
            }
        }
    }
}

extern "C" void kernel_launch(void* const* d_in, const int* in_sizes, int n_in,
                              void* d_out, int out_size, void* d_ws, size_t ws_size,
                              hipStream_t stream) {
    const float* X    = (const float*)d_in[0];
    const float* embd = (const float*)d_in[1];
    const float* W1   = (const float*)d_in[2];
    const float* b1   = (const float*)d_in[3];
    const float* W2   = (const float*)d_in[4];
    const float* b2   = (const float*)d_in[5];
    float* out = (float*)d_out;

    // ws (MiB): t2[0,.06) fidx[.06,.09) ptop[1,9.4) Xp[17,21) Ep[21,29) W1p[37,37.5) W2p[38,38.5)
    // Hp[1,17) aliases ptop (dead after merge). Ep survives gemm1 (A-gather source).
    char* w = (char*)d_ws;
    float* t2 = (float*)w;
    int*  fidx = (int*)(w + 65536);
    uint2* ptop = (uint2*)(w + (1u << 20));
    unsigned short* Hp  = (unsigned short*)(w + (1u << 20));
    unsigned short* Xp  = (unsigned short*)(w + (17u << 20));
    unsigned short* Ep  = (unsigned short*)(w + (21u << 20));
    unsigned short* W1p = (unsigned short*)(w + (37u << 20));
    unsigned short* W2p = (unsigned short*)(w + (38u << 20));

    prep_kernel<<<dim3(4352), dim3(256), 0, stream>>>(
        X, embd, W1, W2, Xp, Ep, W1p, W2p, t2);
    dist_topk_kernel<<<dim3(4096), dim3(512), 0, stream>>>(Xp, Ep, t2, ptop);
    merge_rescreen_kernel<<<dim3(NBN / 4), dim3(256), 0, stream>>>(
        X, embd, ptop, out, fidx);
    // gemm1: h = Zemb*W1^T (+b1, LReLU): A gathered from Ep(hi) via fidx, 1 limb (xh*wh)
    gemm_mfma_kernel<256, 8, 8, 1, 0, 0, 8, 8, 2, 2, 8, true, true>
        <<<dim3(512), dim3(256), 0, stream>>>(Ep, W1p, fidx, b1, nullptr, Hp);
    // gemm2: Zrec = h*W2^T (+b2): A = Hp (hi), B = W2p (hi), 1 limb, 64-row blocks (2/CU)
    gemm_mfma_kernel<1024, 32, 32, 1, 0, 0, 4, 4, 2, 2, 4, false, false>
        <<<dim3(512), dim3(256), 0, stream>>>(Hp, W2p, nullptr, b2, out + OFF_ZREC, nullptr);
}

// Round 16
// 143.343 us; speedup vs baseline: 1.1040x; 1.1040x over previous
//
#include <hip/hip_runtime.h>
#include <float.h>

// B=8, N=1024, D=256, K=16384, H=1024, IN=256
#define DIM      256
#define NK       16384
#define NH       1024
#define NIN      256
#define NBN      8192
#define NT2      128           // NK / 128 (dist n-tiles)

#define OFF_ZREC 0
#define OFF_ZENC (NBN * DIM)
#define OFF_ZEMB (2 * NBN * DIM)

using short8 = __attribute__((ext_vector_type(8))) short;
using f32x4  = __attribute__((ext_vector_type(4))) float;
typedef unsigned long long u64;
typedef unsigned int u32;

#define WAITVM(n)  asm volatile("s_waitcnt vmcnt(" #n ")" ::: "memory")
#define WAITLGKM0  asm volatile("s_waitcnt lgkmcnt(0)" ::: "memory")

template <int N>
__device__ __forceinline__ void waitvm_c() {
    // s_waitcnt imm: vmcnt[3:0]@[3:0], vmcnt[5:4]@[15:14], expcnt@[6:4], lgkmcnt@[11:8]
    __builtin_amdgcn_s_waitcnt(0x0F70 | (N & 0xF) | (((N >> 4) & 3) << 14));
}

__device__ __forceinline__ u32 f2bf(float f) {
    u32 u = __float_as_uint(f);
    return (u + 0x7FFFu + ((u >> 16) & 1u)) >> 16;   // RNE
}
__device__ __forceinline__ float bf2f(u32 h) {
    return __uint_as_float(h << 16);
}
__device__ __forceinline__ u64 umin64(u64 a, u64 b) { return a < b ? a : b; }
__device__ __forceinline__ u32 umin32(u32 a, u32 b) { return a < b ? a : b; }
__device__ __forceinline__ u32 umax32(u32 a, u32 b) { return a > b ? a : b; }

__device__ __forceinline__ void gload16(const void* g, void* l) {
    __builtin_amdgcn_global_load_lds(
        (const __attribute__((address_space(1))) void*)g,
        (__attribute__((address_space(3))) void*)l, 16, 0, 0);
}

// pack one 16x32 chunk of fp32 [rows][KD] into bf16 MFMA fragment(s).
// Fragment (16x16x32 bf16): lane l <-> row = l&15, k = (l>>4)*8 + i.
// dst[rb][unit][lane][8]: hi unit = kc, mid unit = KD/32 + kc.
__device__ __forceinline__ void pack_frag(const float* __restrict__ src,
                                          unsigned short* __restrict__ dst,
                                          int KD, int KBT, int rb, int kc,
                                          int lane, bool with_mid) {
    int row = rb * 16 + (lane & 15);
    int k0  = kc * 32 + (lane >> 4) * 8;
    const float* p = src + (size_t)row * KD + k0;
    float x[8];
    *(float4*)(x)     = *(const float4*)(p);
    *(float4*)(x + 4) = *(const float4*)(p + 4);
    short8 hv, mv;
    #pragma unroll
    for (int i = 0; i < 8; ++i) {
        u32 hb = f2bf(x[i]);
        hv[i] = (short)hb;
        mv[i] = (short)f2bf(x[i] - bf2f(hb));
    }
    *(short8*)(dst + ((size_t)(rb * KBT + kc) * 64 + lane) * 8) = hv;
    if (with_mid)
        *(short8*)(dst + ((size_t)(rb * KBT + KD / 32 + kc) * 64 + lane) * 8) = mv;
}

// ---------------- fused prep: pack X(hi), E(hi), W1(hi), W2(hi) + t2 ----------------
__global__ __launch_bounds__(256) void prep_kernel(
    const float* __restrict__ X, const float* __restrict__ E,
    const float* __restrict__ W1, const float* __restrict__ W2,
    unsigned short* __restrict__ Xp, unsigned short* __restrict__ Ep,
    unsigned short* __restrict__ W1p, unsigned short* __restrict__ W2p,
    float* __restrict__ t2)
{
    int b = blockIdx.x;
    int wid = threadIdx.x >> 6, lane = threadIdx.x & 63;
    if (b < 1024) {                         // X hi: 4096 gids (512 rb x 8 kc)
        int gid = b * 4 + wid;
        pack_frag(X, Xp, 256, 8, gid >> 3, gid & 7, lane, false);
    } else if (b < 3072) {                  // E hi: 8192 gids (1024 rb x 8 kc)
        int gid = (b - 1024) * 4 + wid;
        pack_frag(E, Ep, 256, 8, gid >> 3, gid & 7, lane, false);
    } else if (b < 3200) {                  // W1 hi: 512 gids (64 rb x 8 kc)
        int gid = (b - 3072) * 4 + wid;
        pack_frag(W1, W1p, 256, 8, gid >> 3, gid & 7, lane, false);
    } else if (b < 3328) {                  // W2 hi: 512 gids (16 rb x 32 kc)
        int gid = (b - 3200) * 4 + wid;
        pack_frag(W2, W2p, 1024, 32, gid >> 5, gid & 31, lane, false);
    } else {                                // t2: 1024 blocks x 4 gids x 4 rows
        int gid = (b - 3328) * 4 + wid;
        #pragma unroll
        for (int r = 0; r < 4; ++r) {
            int row = gid * 4 + r;
            float4 v = ((const float4*)(E + (size_t)row * DIM))[lane];
            float s = v.x * v.x + v.y * v.y + v.z * v.z + v.w * v.w;
            #pragma unroll
            for (int off = 32; off > 0; off >>= 1) s += __shfl_down(s, off);
            if (lane == 0) t2[row] = s;
        }
    }
}

// ---------------- MFMA distance (bf16 hi-only), 256x128 tile, 8 waves (4m x 2n) ----------
// Wave tile 64x64 (acc[4][4] -> 2 blocks/CU). BK=32, 2x24KB dbuf, vmcnt(3). No setprio
// (m190/R11: lockstep-barrier structure -> setprio starves co-resident block).
// 2-blocks/CU co-residency is the load-bearing property: every schedule variant that
// lost it (BK=64 R8, 4-buf R6, 3-buf 72KB R15) regressed.
__global__ __launch_bounds__(512, 3) void dist_topk_kernel(
    const unsigned short* __restrict__ Xp, const unsigned short* __restrict__ Ep,
    const float* __restrict__ t2, uint2* __restrict__ ptop)
{
    __shared__ __align__(16) char lds[67584];   // main: 2x24KB; epi: 2 x [256][33] u32

    int bx = blockIdx.x;          // 32 mt x 128 nt
    int mt = bx >> 7, nt = bx & 127;
    int mb0 = mt * 16, nb0 = nt * 8;
    int m0 = mt * 256, n0 = nt * 128;

    int tid = threadIdx.x;
    int wid = tid >> 6, lane = tid & 63;
    int wm = wid >> 1, wn = wid & 1;            // 4 x 2 wave grid; wave = 64x64 out

    f32x4 acc[4][4] = {};

    auto STAGE = [&](int s) {                   // stage K32-slice s into buffer s&1
        char* L = lds + (s & 1) * 24576;
        #pragma unroll
        for (int c = 0; c < 3; ++c) {
            int ci = wid * 3 + c;               // 0..23: A rb 0..15, B rb 0..7
            if (ci < 16)
                gload16(Xp + ((size_t)((mb0 + ci) * 8 + s) * 64 + lane) * 8,
                        L + ci * 1024);
            else
                gload16(Ep + ((size_t)((nb0 + (ci - 16)) * 8 + s) * 64 + lane) * 8,
                        L + 16384 + (ci - 16) * 1024);
        }
    };

    STAGE(0);
    #pragma unroll
    for (int s = 0; s < 8; ++s) {
        if (s < 7) { STAGE(s + 1); WAITVM(3); }   // wait stage-s loads only
        else       { WAITVM(0); }
        __builtin_amdgcn_s_barrier();
        __builtin_amdgcn_sched_barrier(0);
        const char* LA = lds + (s & 1) * 24576;
        const char* LB = LA + 16384;
        short8 a[4], b[4];
        #pragma unroll
        for (int i = 0; i < 4; ++i)
            a[i] = *(const short8*)(LA + ((wm * 4 + i) << 10) + (lane << 4));
        #pragma unroll
        for (int j = 0; j < 4; ++j)
            b[j] = *(const short8*)(LB + ((wn * 4 + j) << 10) + (lane << 4));
        #pragma unroll
        for (int i = 0; i < 4; ++i)
            #pragma unroll
            for (int j = 0; j < 4; ++j)
                acc[i][j] = __builtin_amdgcn_mfma_f32_16x16x32_bf16(
                    a[i], b[j], acc[i][j], 0, 0, 0);
        WAITLGKM0;
        __builtin_amdgcn_sched_barrier(0);
        __builtin_amdgcn_s_barrier();
    }

    // ---- epilogue: per-row top-2 over this block's 128 cols, single pass ----
    // C frag: col = lane&15, row = (lane>>4)*4 + r.  Keys: positive floats
    // (score + 4096 > 0) are uint-ordered; key = (bits & 0xFFFFFF00) | local_col.
    // Write slot rotated by 4*lg: bank = const + col + 8*lg -> 2-way max.
    int col_l = lane & 15, lg = lane >> 4;
    float t2b[4];
    #pragma unroll
    for (int j = 0; j < 4; ++j) t2b[j] = t2[n0 + wn * 64 + j * 16 + col_l] + 4096.0f;

    u32* cand0 = (u32*)lds;                     // [256 rows][33 slots]
    u32* cand1 = cand0 + 256 * 33;
    int slot = (wn * 16 + col_l + 4 * lg) & 31; // per-row bijective, lg-rotated
    #pragma unroll
    for (int i = 0; i < 4; ++i)
        #pragma unroll
        for (int r = 0; r < 4; ++r) {
            u32 b0 = 0xFFFFFFFFu, b1 = 0xFFFFFFFFu;
            #pragma unroll
            for (int j = 0; j < 4; ++j) {
                float sc = fmaf(-2.0f, acc[i][j][r], t2b[j]);
                u32 u = (__float_as_uint(sc) & 0xFFFFFF00u)
                      | (u32)(wn * 64 + j * 16 + col_l);
                u32 t = umin32(b0, u);
                b1 = umin32(b1, umax32(b0, u));
                b0 = t;
            }
            int row = wm * 64 + i * 16 + lg * 4 + r;             // 0..255
            cand0[row * 33 + slot] = b0;
            cand1[row * 33 + slot] = b1;
        }
    __syncthreads();
    // scan: 2 threads per row, sequential slots (bank = row+16*part+t -> 2-way, free)
    {
        int row = tid >> 1, part = tid & 1;
        u32 c0 = 0xFFFFFFFFu, c1 = 0xFFFFFFFFu;
        #pragma unroll 4
        for (int t = 0; t < 16; ++t) {
            int sl = part * 16 + t;
            u32 a0 = cand0[row * 33 + sl];
            u32 a1 = cand1[row * 33 + sl];
            u32 lo = umin32(c0, a0);
            c1 = umin32(umax32(c0, a0), umin32(c1, a1));
            c0 = lo;
        }
        u32 a0 = __shfl_xor(c0, 1);
        u32 a1 = __shfl_xor(c1, 1);
        u32 lo = umin32(c0, a0);
        c1 = umin32(umax32(c0, a0), umin32(c1, a1));
        c0 = lo;
        if (part == 0)                           // transposed: [nt][q] -> coalesced
            ptop[(size_t)nt * NBN + (m0 + row)] = make_uint2(c0, c1);
    }
}

// ---------------- merge -> top-3 -> exact fp64 rescreen -> gather + final idx ----------------
__global__ __launch_bounds__(256) void merge_rescreen_kernel(
    const float* __restrict__ X, const float* __restrict__ E,
    const uint2* __restrict__ ptop, float* __restrict__ out, int* __restrict__ fidx)
{
    int wid = threadIdx.x >> 6, lane = threadIdx.x & 63;
    int q = blockIdx.x * 4 + wid;
    uint2 A = ptop[(size_t)(lane * 2)     * NBN + q];
    uint2 B = ptop[(size_t)(lane * 2 + 1) * NBN + q];
    // rebuild globally-ordered keys: [24b score @ bits 14..37 | 14b global k]
    u64 k[4];
    k[0] = ((u64)(A.x & 0xFFFFFF00u) << 6) | (u32)((lane * 2) * 128 + (A.x & 0xFF));
    k[1] = ((u64)(A.y & 0xFFFFFF00u) << 6) | (u32)((lane * 2) * 128 + (A.y & 0xFF));
    k[2] = ((u64)(B.x & 0xFFFFFF00u) << 6) | (u32)((lane * 2 + 1) * 128 + (B.x & 0xFF));
    k[3] = ((u64)(B.y & 0xFFFFFF00u) << 6) | (u32)((lane * 2 + 1) * 128 + (B.y & 0xFF));
    int cand[3];
    #pragma unroll
    for (int pass = 0; pass < 3; ++pass) {
        u64 m = umin64(umin64(k[0], k[1]), umin64(k[2], k[3]));
        #pragma unroll
        for (int mask = 1; mask < 64; mask <<= 1)
            m = umin64(m, (u64)__shfl_xor((unsigned long long)m, mask));
        cand[pass] = (int)(m & 0x3FFF);
        #pragma unroll
        for (int t = 0; t < 4; ++t) if (k[t] == m) k[t] = ~0ull;
    }
    float4 qv = ((const float4*)(X + (size_t)q * DIM))[lane];
    double bd = 1e300; int bi = NK;
    #pragma unroll 1
    for (int c = 0; c < 3; ++c) {
        int idx = cand[c];
        float4 ev = ((const float4*)(E + (size_t)idx * DIM))[lane];
        double d0 = (double)qv.x - (double)ev.x;
        double d1 = (double)qv.y - (double)ev.y;
        double d2 = (double)qv.z - (double)ev.z;
        double d3 = (double)qv.w - (double)ev.w;
        double s = d0 * d0 + d1 * d1 + d2 * d2 + d3 * d3;
        #pragma unroll
        for (int off = 32; off > 0; off >>= 1) s += __shfl_down(s, off);
        s = __shfl(s, 0);
        if (s < bd || (s == bd && idx < bi)) { bd = s; bi = idx; }
    }
    float4 ev = ((const float4*)(E + (size_t)bi * DIM))[lane];
    ((float4*)(out + OFF_ZEMB + (size_t)q * DIM))[lane] = ev;
    ((float4*)(out + OFF_ZENC + (size_t)q * DIM))[lane] = qv;
    if (lane == 0) fidx[q] = bi;
}

// ---------------- multi-limb bf16 MFMA GEMM: C[M][N] = A[M][KD]*B[N][KD]^T + bias ----------
// GATHER: A-fragments gathered per-lane from Ap (codebook pack) via selidx.
// G1: bias+LeakyReLU, repack hi-limb into Hp (gemm2 A-fragment layout, 32 units).
// Counted-vmcnt dual-barrier pipeline. Geometry: NRB_A x NRB_B row/col blocks, WMxWN waves.
template <int KD, int A_KBT, int B_KBT, int NPROD, int AO1, int BO1,
          int NRB_A, int NRB_B, int WM, int WN, int NT, bool G1, bool GATHER>
__global__ __launch_bounds__(64 * WM * WN) void gemm_mfma_kernel(
    const unsigned short* __restrict__ Ap, const unsigned short* __restrict__ Bp,
    const int* __restrict__ selidx, const float* __restrict__ bias,
    float* __restrict__ C, unsigned short* __restrict__ Hp)
{
    constexpr int KQ    = KD / 64;
    constexpr int STEPS = NPROD * KQ;
    constexpr int WI    = NRB_A / WM;
    constexpr int FJ    = NRB_B / WN;
    constexpr int CA    = NRB_A * 2;
    constexpr int CB    = NRB_B * 2;
    constexpr int NW    = WM * WN;
    constexpr int PW    = (CA + CB) / NW;
    constexpr int BUFSZ = (CA + CB) * 1024;
    constexpr int LDSSZ = G1 ? 65536 : 2 * BUFSZ;

    __shared__ __align__(16) char lds[LDSSZ];

    int bx = blockIdx.x;
    int mt = bx / NT, nt = bx % NT;
    int mb0 = mt * NRB_A, nb0 = nt * NRB_B;
    int m0 = mt * (NRB_A * 16), n0 = nt * (NRB_B * 16);

    int tid = threadIdx.x;
    int wid = tid >> 6, lane = tid & 63;
    int wm = wid / WN, wn = wid % WN;

    f32x4 acc[WI][FJ] = {};

    auto STAGE = [&](int s, int b) {
        int p = s / KQ, kq = s % KQ;
        int akb = (p == 0 ? 0 : AO1) + kq * 2;
        int bkb = (p == 0 ? 0 : BO1) + kq * 2;
        char* LA = lds + b * BUFSZ;
        char* LB = LA + CA * 1024;
        #pragma unroll
        for (int r = 0; r < PW; ++r) {
            int ci = wid * PW + r;
            if (ci < CA) {
                int rbl = ci >> 1, kbl = ci & 1;
                size_t ga;
                if constexpr (GATHER) {
                    int sel = selidx[(mb0 + rbl) * 16 + (lane & 15)];
                    ga = ((size_t)((sel >> 4) * A_KBT + akb + kbl) * 64
                          + (lane >> 4) * 16 + (sel & 15)) * 8;
                } else {
                    ga = ((size_t)((mb0 + rbl) * A_KBT + akb + kbl) * 64 + lane) * 8;
                }
                gload16(Ap + ga, LA + ci * 1024);
            } else {
                int cj = ci - CA, rbl = cj >> 1, kbl = cj & 1;
                gload16(Bp + ((size_t)((nb0 + rbl) * B_KBT + bkb + kbl) * 64 + lane) * 8,
                        LB + cj * 1024);
            }
        }
    };

    STAGE(0, 0);
    for (int s = 0; s < STEPS; ++s) {
        int cur = s & 1;
        if (s + 1 < STEPS) { STAGE(s + 1, cur ^ 1); waitvm_c<PW>(); }
        else               { waitvm_c<0>(); }
        __builtin_amdgcn_s_barrier();
        __builtin_amdgcn_sched_barrier(0);
        const char* LA = lds + cur * BUFSZ;
        const char* LB = LA + CA * 1024;
        #pragma unroll
        for (int kk = 0; kk < 2; ++kk) {
            short8 a[WI], b[FJ];
            #pragma unroll
            for (int i = 0; i < WI; ++i)
                a[i] = *(const short8*)(LA + (((wm * WI + i) * 2 + kk) << 10) + (lane << 4));
            #pragma unroll
            for (int j = 0; j < FJ; ++j)
                b[j] = *(const short8*)(LB + (((wn * FJ + j) * 2 + kk) << 10) + (lane << 4));
            #pragma unroll
            for (int i = 0; i < WI; ++i)
                #pragma unroll
                for (int j = 0; j < FJ; ++j)
                    acc[i][j] = __builtin_amdgcn_mfma_f32_16x16x32_bf16(
                        a[i], b[j], acc[i][j], 0, 0, 0);
        }
        WAITLGKM0;
        __builtin_amdgcn_sched_barrier(0);
        __builtin_amdgcn_s_barrier();
    }

    int col_l = lane & 15, lg = lane >> 4;
    if (!G1) {
        #pragma unroll
        for (int j = 0; j < FJ; ++j) {
            int n = n0 + wn * (FJ * 16) + j * 16 + col_l;
            float bb = bias[n];
            #pragma unroll
            for (int i = 0; i < WI; ++i)
                #pragma unroll
                for (int r = 0; r < 4; ++r) {
                    int m = m0 + wm * (WI * 16) + i * 16 + lg * 4 + r;
                    C[(size_t)m * (NT * NRB_B * 16) + n] = acc[i][j][r] + bb;
                }
        }
    } else {
        // bias + LeakyReLU + bf16(hi) -> swizzled LDS u16 tile -> repack to Hp frags
        // (fixed geometry: NRB_A=8, NRB_B=8, WM=WN=2)
        unsigned short* lds16 = (unsigned short*)lds;
        #pragma unroll
        for (int j = 0; j < FJ; ++j) {
            int coln = wn * 64 + j * 16 + col_l;
            float bb = bias[n0 + coln];
            #pragma unroll
            for (int i = 0; i < WI; ++i)
                #pragma unroll
                for (int r = 0; r < 4; ++r) {
                    int row = wm * 64 + i * 16 + lg * 4 + r;
                    float v = acc[i][j][r] + bb;
                    v = fmaxf(v, 0.1f * v);
                    int sw = ((row >> 2) & 3) << 3;
                    lds16[row * 128 + (coln ^ sw)] = (unsigned short)f2bf(v);
                }
        }
        __syncthreads();
        #pragma unroll
        for (int rbw = 0; rbw < 2; ++rbw) {
            int rrb = wid * 2 + rbw;
            int rloc = lane & 15, ls = lane >> 4;
            int row = rrb * 16 + rloc;
            int sw  = ((row >> 2) & 3) << 3;
            #pragma unroll
            for (int kc = 0; kc < 4; ++kc) {
                int c0 = (kc * 32 + ls * 8) ^ sw;
                short8 h8 = *(const short8*)(lds16 + row * 128 + c0);
                int ku = nt * 4 + kc;              // unit within KD2=1024 hi (32 units)
                *(short8*)(Hp + ((size_t)((mb0 + rrb) * 32 + ku) * 64 + lane) * 8) = h8;
            }
        }
    }
}

extern "C" void kernel_launch(void* const* d_in, const int* in_sizes, int n_in,
                              void* d_out, int out_size, void* d_ws, size_t ws_size,
                              hipStream_t stream) {
    const float* X    = (const float*)d_in[0];
    const float* embd = (const float*)d_in[1];
    const float* W1   = (const float*)d_in[2];
    const float* b1   = (const float*)d_in[3];
    const float* W2   = (const float*)d_in[4];
    const float* b2   = (const float*)d_in[5];
    float* out = (float*)d_out;

    // ws (MiB): t2[0,.06) fidx[.06,.09) ptop[1,9.4) Xp[17,21) Ep[21,29) W1p[37,37.5) W2p[38,38.5)
    // Hp[1,17) aliases ptop (dead after merge). Ep survives gemm1 (A-gather source).
    char* w = (char*)d_ws;
    float* t2 = (float*)w;
    int*  fidx = (int*)(w + 65536);
    uint2* ptop = (uint2*)(w + (1u << 20));
    unsigned short* Hp  = (unsigned short*)(w + (1u << 20));
    unsigned short* Xp  = (unsigned short*)(w + (17u << 20));
    unsigned short* Ep  = (unsigned short*)(w + (21u << 20));
    unsigned short* W1p = (unsigned short*)(w + (37u << 20));
    unsigned short* W2p = (unsigned short*)(w + (38u << 20));

    prep_kernel<<<dim3(4352), dim3(256), 0, stream>>>(
        X, embd, W1, W2, Xp, Ep, W1p, W2p, t2);
    dist_topk_kernel<<<dim3(4096), dim3(512), 0, stream>>>(Xp, Ep, t2, ptop);
    merge_rescreen_kernel<<<dim3(NBN / 4), dim3(256), 0, stream>>>(
        X, embd, ptop, out, fidx);
    // gemm1: h = Zemb*W1^T (+b1, LReLU): A gathered from Ep(hi) via fidx, 1 limb (xh*wh)
    gemm_mfma_kernel<256, 8, 8, 1, 0, 0, 8, 8, 2, 2, 8, true, true>
        <<<dim3(512), dim3(256), 0, stream>>>(Ep, W1p, fidx, b1, nullptr, Hp);
    // gemm2: Zrec = h*W2^T (+b2): A = Hp (hi), B = W2p (hi), 1 limb, 64-row blocks (2/CU)
    gemm_mfma_kernel<1024, 32, 32, 1, 0, 0, 4, 4, 2, 2, 4, false, false>
        <<<dim3(512), dim3(256), 0, stream>>>(Hp, W2p, nullptr, b2, out + OFF_ZREC, nullptr);
}